// Round 8
// baseline (173.095 us; speedup 1.0000x reference)
//
#include <hip/hip_runtime.h>
#include <hip/hip_bf16.h>

#define BN 2
#define SDIM 2048
#define EDIM 1024
#define HN 16
#define DDIM 64

typedef __attribute__((ext_vector_type(8))) short bfrag;
typedef __attribute__((ext_vector_type(4))) float ffrag;

__device__ __forceinline__ ffrag mfma16(bfrag a, bfrag b, ffrag c) {
    return __builtin_amdgcn_mfma_f32_16x16x32_bf16(a, b, c, 0, 0, 0);
}

__device__ __forceinline__ ushort f2bf(float f) {
    union { float f; unsigned u; } un;
    un.f = f;
    unsigned u = un.u;
    u += 0x7fffu + ((u >> 16) & 1u);   // RNE
    return (ushort)(u >> 16);
}

__device__ __forceinline__ uint pkbf2(float a, float b) {
    __hip_bfloat162 h = __float22bfloat162_rn(make_float2(a, b));
    union { __hip_bfloat162 h; uint u; } cv;
    cv.h = h;
    return cv.u;
}

// async global->LDS: 16B/lane; LDS dest = wave-uniform base + lane*16
__device__ __forceinline__ void gld16(const void* g, void* l) {
    __builtin_amdgcn_global_load_lds((const __attribute__((address_space(1))) void*)g,
                                     (__attribute__((address_space(3))) void*)l,
                                     16, 0, 0);
}

// ---------------- fused fp32 -> bf16 conversion ----------------
__global__ __launch_bounds__(256) void to_bf16_3(const float* __restrict__ a, ushort* __restrict__ oa, int na,
                                                 const float* __restrict__ b, ushort* __restrict__ ob, int nb,
                                                 const float* __restrict__ c, ushort* __restrict__ oc, int nc) {
    int i = (blockIdx.x * 256 + threadIdx.x) * 4;
    const float* src;
    ushort* dst;
    if (i < na)                { src = a + i;            dst = oa + i; }
    else if (i < na + nb)      { src = b + (i - na);     dst = ob + (i - na); }
    else if (i < na + nb + nc) { src = c + (i - na - nb); dst = oc + (i - na - nb); }
    else return;
    float4 v = *(const float4*)src;
    uint2 u;
    u.x = pkbf2(v.x, v.y);
    u.y = pkbf2(v.z, v.w);
    *(uint2*)dst = u;
}

// ---------------- bf16 BT-GEMM, BK=64, dbuf async prefetch, one barrier/iter ----------------
// Tile: (MI*32) x 128, 4 waves (2x2), wave = (MI*16) x 64. Rotate swizzle:
// 16B chunk c of row r stored at slot (c + r) & 7.
// Double-buffered LDS: prefetch tile k+1 via gld16 BEFORE computing tile k;
// the single end-of-iter barrier drains both lgkmcnt (reads) and vmcnt (prefetch).
// MODE 0: fp32 out row-major. MODE 1: qkv scatter, V transposed to [b,h,d,s].
template <int MODE, int MI>
__global__ __launch_bounds__(256) void gemm_bt(const ushort* __restrict__ A,
                                               const ushort* __restrict__ Bt,
                                               const float* __restrict__ bias,
                                               void* __restrict__ Cout,
                                               int M, int N, int K) {
    __shared__ ushort As[2][MI * 32 * 64];
    __shared__ ushort Bs[2][128 * 64];

    const int tid  = threadIdx.x;
    const int wave = tid >> 6;
    const int lane = tid & 63;
    const int ln16 = lane & 15;
    const int quad = lane >> 4;
    const int wm = wave >> 1, wn = wave & 1;
    const int bm = blockIdx.x * (MI * 32);
    const int bn = blockIdx.y * 128;

    auto stage = [&](int k0, int buf) {
#pragma unroll
        for (int p = 0; p < MI; ++p) {
            int g0 = p * 256 + wave * 64;        // wave-uniform chunk base
            int g  = g0 + lane;
            int r  = g >> 3;
            int c  = ((g & 7) - r) & 7;          // inverse swizzle
            gld16(A + (size_t)(bm + r) * K + k0 + c * 8, (ushort*)&As[buf][0] + g0 * 8);
        }
#pragma unroll
        for (int p = 0; p < 4; ++p) {
            int g0 = p * 256 + wave * 64;
            int g  = g0 + lane;
            int r  = g >> 3;
            int c  = ((g & 7) - r) & 7;
            gld16(Bt + (size_t)(bn + r) * K + k0 + c * 8, (ushort*)&Bs[buf][0] + g0 * 8);
        }
    };

    ffrag acc[MI][4];
#pragma unroll
    for (int mi = 0; mi < MI; ++mi)
#pragma unroll
        for (int ni = 0; ni < 4; ++ni)
            acc[mi][ni] = (ffrag){0.f, 0.f, 0.f, 0.f};

    stage(0, 0);
    __syncthreads();

    const int niter = K >> 6;
    for (int it = 0; it < niter; ++it) {
        const int buf = it & 1;
        if (it + 1 < niter) stage((it + 1) << 6, buf ^ 1);   // async prefetch

        const ushort* Ab = &As[buf][0];
        const ushort* Bb = &Bs[buf][0];
#pragma unroll
        for (int kb = 0; kb < 2; ++kb) {
            bfrag af[MI], bf[4];
#pragma unroll
            for (int mi = 0; mi < MI; ++mi) {
                int r = wm * (MI * 16) + mi * 16 + ln16;
                af[mi] = *(const bfrag*)&Ab[r * 64 + ((kb * 4 + quad + r) & 7) * 8];
            }
#pragma unroll
            for (int ni = 0; ni < 4; ++ni) {
                int r = wn * 64 + ni * 16 + ln16;
                bf[ni] = *(const bfrag*)&Bb[r * 64 + ((kb * 4 + quad + r) & 7) * 8];
            }
#pragma unroll
            for (int mi = 0; mi < MI; ++mi)
#pragma unroll
                for (int ni = 0; ni < 4; ++ni)
                    acc[mi][ni] = mfma16(af[mi], bf[ni], acc[mi][ni]);
        }
        __syncthreads();   // drains reads of buf + prefetch into buf^1
    }

#pragma unroll
    for (int mi = 0; mi < MI; ++mi) {
#pragma unroll
        for (int ni = 0; ni < 4; ++ni) {
            int col = bn + wn * 64 + ni * 16 + ln16;
            float bc = bias[col];
            int row0 = bm + wm * (MI * 16) + mi * 16 + quad * 4;
            if (MODE == 0) {
#pragma unroll
                for (int reg = 0; reg < 4; ++reg)
                    ((float*)Cout)[(size_t)(row0 + reg) * N + col] = acc[mi][ni][reg] + bc;
            } else {
                int which = col >> 10;        // wave-uniform: 0=q 1=k 2=v
                int rem = col & 1023;
                int h = rem >> 6;
                int d = rem & 63;
                int b = row0 >> 11;
                int s0 = row0 & 2047;
                if (which == 2) {
                    // V transposed [b,h,d,s]: 4 regs = 4 consecutive s -> 8B store
                    float v0 = acc[mi][ni][0] + bc, v1 = acc[mi][ni][1] + bc;
                    float v2 = acc[mi][ni][2] + bc, v3 = acc[mi][ni][3] + bc;
                    uint2 pk;
                    pk.x = pkbf2(v0, v1);
                    pk.y = pkbf2(v2, v3);
                    size_t dst = 2ull * (BN * HN * SDIM * DDIM) +
                                 (((size_t)(b * HN + h)) * DDIM + d) * SDIM + s0;
                    *(uint2*)((ushort*)Cout + dst) = pk;
                } else {
                    float sc = (which == 0) ? 0.125f : 1.f;
#pragma unroll
                    for (int reg = 0; reg < 4; ++reg) {
                        float v = (acc[mi][ni][reg] + bc) * sc;
                        size_t dst = (size_t)which * (BN * HN * SDIM * DDIM) +
                                     (((size_t)(b * HN + h)) * SDIM + s0 + reg) * DDIM + d;
                        ((ushort*)Cout)[dst] = f2bf(v);
                    }
                }
            }
        }
    }
}

// ---------------- per-head per-tile V sums (parallel) ----------------
// grid (32, 8), 256 threads = 4 tiles x 64 d. T[bh][tile][d] = sum_{s in tile} V[d][s].
__global__ __launch_bounds__(256) void vsum_tiles(const ushort* __restrict__ Vtb,
                                                  float* __restrict__ T) {
    const int bh   = blockIdx.x;
    const int tile = blockIdx.y * 4 + (threadIdx.x >> 6);
    const int d    = threadIdx.x & 63;
    const ushort* row = Vtb + ((size_t)bh * DDIM + d) * SDIM + tile * 64;
    float s = 0.f;
#pragma unroll
    for (int j = 0; j < 64; j += 8) {
        uint4 v = *(const uint4*)(row + j);
        ushort tmp[8];
        *(uint4*)tmp = v;
#pragma unroll
        for (int e = 0; e < 8; ++e) {
            union { float f; uint u; } c;
            c.u = ((uint)tmp[e]) << 16;
            s += c.f;
        }
    }
    T[((size_t)bh * 32 + tile) * 64 + d] = s;
}

// ---------------- flash attention with near-band + closed-form far field ----------------
__global__ __launch_bounds__(512, 4) void flash_attn(const ushort* __restrict__ Qb,
                                                     const ushort* __restrict__ Kb,
                                                     const ushort* __restrict__ Vtb,
                                                     const float* __restrict__ decay_ptr,
                                                     const float* __restrict__ T,
                                                     ushort* __restrict__ Ob) {
    __shared__ ushort KVs[2][2][4096];   // [buf][K / Vt][64 rows x 8 chunks, swizzled]
    __shared__ ushort Pb[128][72];       // Q staging, then P exchange (per-wave rows)
    __shared__ float  Fv[64];            // far-field V sum per d

    const int tid  = threadIdx.x;
    const int wave = tid >> 6;
    const int lane = tid & 63;
    const int ln16 = lane & 15;
    const int quad = lane >> 4;

    const int bh = blockIdx.y;
    const int q0 = blockIdx.x * 128;
    const size_t head_off = (size_t)bh * SDIM * DDIM;
    const float absa = fabsf(decay_ptr[0]);
    const float LOG2E = 1.442695041f;
    const float M0L2 = -17.3123404f;     // -12 * log2(e)
    const float E12 = 6.144212353e-6f;   // e^-12

    // near band: tiles with a*min-dist(block q-range, tile) < 16
    int Dstar = (absa > 1e-5f) ? (int)ceilf(16.0f / absa) : (4 * SDIM);
    int lo = q0 - 63 - Dstar; if (lo < 0) lo = 0;
    int hi = q0 + 127 + Dstar; if (hi > SDIM - 1) hi = SDIM - 1;
    const int tlo = lo >> 6;
    const int thi = hi >> 6;
    const int ntiles = thi - tlo + 1;

    // far-field V sums from per-tile sums (overlapped with Q/K staging)
    if (tid < 64) {
        const float* Tp = T + (size_t)bh * 32 * 64;
        float s = 0.f;
        for (int k = 0; k < tlo; ++k)      s += Tp[k * 64 + tid];
        for (int k = thi + 1; k < 32; ++k) s += Tp[k * 64 + tid];
        Fv[tid] = s;
    }

    auto stageKV = [&](int t0, int buf) {
        int g0 = wave * 64;
        int g  = g0 + lane;
        int r  = g >> 3;
        int c  = (g - r) & 7;            // inverse swizzle
        gld16(Kb  + head_off + (size_t)(t0 + r) * DDIM + c * 8,
              (ushort*)&KVs[buf][0][0] + g0 * 8);
        gld16(Vtb + head_off + (size_t)r * SDIM + t0 + c * 8,
              (ushort*)&KVs[buf][1][0] + g0 * 8);
    };

    // stage Q (128x64) into Pb + first K/V tile into buf 0
#pragma unroll
    for (int p = 0; p < 2; ++p) {
        int idx = p * 512 + tid;
        int r = idx >> 3, c = (idx & 7) * 8;
        *(uint4*)&Pb[r][c] = *(const uint4*)(Qb + head_off + (size_t)(q0 + r) * DDIM + c);
    }
    stageKV(tlo * 64, 0);
    __syncthreads();

    bfrag aq[2];
#pragma unroll
    for (int kb = 0; kb < 2; ++kb)
        aq[kb] = *(const bfrag*)&Pb[wave * 16 + ln16][kb * 32 + quad * 8];

    bfrag ones;
#pragma unroll
    for (int i = 0; i < 8; ++i) ones[i] = (short)0x3F80;   // bf16 1.0

    float EcB[4], FcB[4], Epw[4], Fpw[4];
#pragma unroll
    for (int reg = 0; reg < 4; ++reg) {
        int cr = quad * 4 + reg;
        EcB[reg] = __expf(-absa * (float)(15 - cr));
        FcB[reg] = __expf(-absa * (float)cr);
    }
#pragma unroll
    for (int ni = 0; ni < 4; ++ni) {
        Epw[ni] = __expf(-absa * (float)(16 * (3 - ni)));
        Fpw[ni] = __expf(-absa * (float)(16 * ni));
    }
    const float Er = __expf(-absa * (float)ln16);
    const float Fr = __expf(-absa * (float)(15 - ln16));

    ffrag lacc = (ffrag){0.f, 0.f, 0.f, 0.f};
    ffrag o[4];
#pragma unroll
    for (int ni = 0; ni < 4; ++ni) o[ni] = (ffrag){0.f, 0.f, 0.f, 0.f};

    const int m = wave * 16 + ln16;

    for (int it = 0; it < ntiles; ++it) {
        const int t0 = (tlo + it) * 64;
        const int buf = it & 1;
        if (it + 1 < ntiles) stageKV(t0 + 64, buf ^ 1);   // async prefetch

        const ushort* Kt = &KVs[buf][0][0];
        const ushort* Vt = &KVs[buf][1][0];

        // S^T = K * Q^T
        ffrag sc[4];
#pragma unroll
        for (int ni = 0; ni < 4; ++ni) {
            ffrag a = (ffrag){0.f, 0.f, 0.f, 0.f};
            const int rk = ni * 16 + ln16;
#pragma unroll
            for (int kb = 0; kb < 2; ++kb) {
                bfrag kf = *(const bfrag*)&Kt[rk * 64 + ((kb * 4 + quad + rk) & 7) * 8];
                a = mfma16(kf, aq[kb], a);
            }
            sc[ni] = a;
        }

        // p = exp2(fma(s, decay*log2e, -12*log2e)); pack P to own-wave LDS rows
        const int ds = q0 + wave * 16 - t0;
        float hh = 0.f;
        if (ds >= 64)       hh = __expf(-absa * (float)(ds - 63)) * Er * LOG2E;
        else if (ds <= -16) hh = __expf(-absa * (float)(-ds - 15)) * Fr * LOG2E;

#pragma unroll
        for (int ni = 0; ni < 4; ++ni) {
            float f0, f1, f2, f3;
            if (ds >= 64) {
                float hn = hh * Epw[ni];
                f0 = hn * EcB[0]; f1 = hn * EcB[1]; f2 = hn * EcB[2]; f3 = hn * EcB[3];
            } else if (ds <= -16) {
                float hn = hh * Fpw[ni];
                f0 = hn * FcB[0]; f1 = hn * FcB[1]; f2 = hn * FcB[2]; f3 = hn * FcB[3];
            } else {
                int c0 = ni * 16 + quad * 4;
                f0 = __expf(-absa * fabsf((float)(ds + ln16 - c0)))     * LOG2E;
                f1 = __expf(-absa * fabsf((float)(ds + ln16 - c0 - 1))) * LOG2E;
                f2 = __expf(-absa * fabsf((float)(ds + ln16 - c0 - 2))) * LOG2E;
                f3 = __expf(-absa * fabsf((float)(ds + ln16 - c0 - 3))) * LOG2E;
            }
            float p0 = exp2f(fmaf(sc[ni][0], f0, M0L2));
            float p1 = exp2f(fmaf(sc[ni][1], f1, M0L2));
            float p2 = exp2f(fmaf(sc[ni][2], f2, M0L2));
            float p3 = exp2f(fmaf(sc[ni][3], f3, M0L2));
            uint2 pk;
            pk.x = pkbf2(p0, p1);
            pk.y = pkbf2(p2, p3);
            *(uint2*)&Pb[m][ni * 16 + quad * 4] = pk;   // own-wave rows: no barrier
        }

        bfrag ap[2];
#pragma unroll
        for (int kb = 0; kb < 2; ++kb)
            ap[kb] = *(const bfrag*)&Pb[m][kb * 32 + quad * 8];

#pragma unroll
        for (int kb = 0; kb < 2; ++kb)
            lacc = mfma16(ones, ap[kb], lacc);
#pragma unroll
        for (int ni = 0; ni < 4; ++ni) {
            const int rv = ni * 16 + ln16;
#pragma unroll
            for (int kb = 0; kb < 2; ++kb) {
                bfrag vf = *(const bfrag*)&Vt[rv * 64 + ((kb * 4 + quad + rv) & 7) * 8];
                o[ni] = mfma16(vf, ap[kb], o[ni]);
            }
        }
        __syncthreads();
    }

    // epilogue: add far field, normalize, store
    const float farl = E12 * (float)(SDIM - 64 * ntiles);
    const float inv = 1.f / (lacc[0] + farl);
    const int b = bh / HN, h = bh % HN;
    const int s = q0 + m;
    ushort* dst = Ob + ((size_t)(b * SDIM + s)) * EDIM + h * DDIM + quad * 4;
#pragma unroll
    for (int ni = 0; ni < 4; ++ni) {
        int d0 = ni * 16 + quad * 4;
        float v0 = (o[ni][0] + E12 * Fv[d0 + 0]) * inv;
        float v1 = (o[ni][1] + E12 * Fv[d0 + 1]) * inv;
        float v2 = (o[ni][2] + E12 * Fv[d0 + 2]) * inv;
        float v3 = (o[ni][3] + E12 * Fv[d0 + 3]) * inv;
        uint2 pk;
        pk.x = pkbf2(v0, v1);
        pk.y = pkbf2(v2, v3);
        *(uint2*)(dst + ni * 16) = pk;
    }
}

extern "C" void kernel_launch(void* const* d_in, const int* in_sizes, int n_in,
                              void* d_out, int out_size, void* d_ws, size_t ws_size,
                              hipStream_t stream) {
    const float* x      = (const float*)d_in[0];
    const float* Wqkv_w = (const float*)d_in[1];
    const float* Wqkv_b = (const float*)d_in[2];
    const float* out_w  = (const float*)d_in[3];
    const float* out_b  = (const float*)d_in[4];
    const float* dd     = (const float*)d_in[5];

    char* ws = (char*)d_ws;
    const size_t MB = 1024 * 1024;
    ushort* xb    = (ushort*)(ws + 0 * MB);    // dead after gemm<1>; T reuses it
    ushort* wqkvb = (ushort*)(ws + 8 * MB);
    ushort* owb   = (ushort*)(ws + 14 * MB);
    ushort* qkvb  = (ushort*)(ws + 16 * MB);   // q,k:[b,h,s,d] v:[b,h,d,s]
    ushort* ob    = (ushort*)(ws + 40 * MB);
    float*  Tp    = (float*)(ws + 0 * MB);     // 32*32*64*4 = 256 KB (after gemm<1>)

    const int n_x = BN * SDIM * EDIM;
    const int n_w = 3 * EDIM * EDIM;
    const int n_o = EDIM * EDIM;
    const int HSD = BN * HN * SDIM * DDIM;

    to_bf16_3<<<(n_x + n_w + n_o) / 1024, 256, 0, stream>>>(
        x, xb, n_x, Wqkv_w, wqkvb, n_w, out_w, owb, n_o);

    gemm_bt<1, 4><<<dim3(32, 24), 256, 0, stream>>>(xb, wqkvb, Wqkv_b, (void*)qkvb,
                                                    BN * SDIM, 3 * EDIM, EDIM);

    vsum_tiles<<<dim3(32, 8), 256, 0, stream>>>(qkvb + 2 * HSD, Tp);

    flash_attn<<<dim3(SDIM / 128, BN * HN), 512, 0, stream>>>(
        qkvb, qkvb + HSD, qkvb + 2 * HSD, dd, Tp, ob);

    gemm_bt<0, 2><<<dim3(64, 8), 256, 0, stream>>>(ob, owb, out_b, d_out,
                                                   BN * SDIM, EDIM, EDIM);
}

// Round 9
// 170.241 us; speedup vs baseline: 1.0168x; 1.0168x over previous
//
#include <hip/hip_runtime.h>
#include <hip/hip_bf16.h>

#define BN 2
#define SDIM 2048
#define EDIM 1024
#define HN 16
#define DDIM 64

typedef __attribute__((ext_vector_type(8))) short bfrag;
typedef __attribute__((ext_vector_type(4))) float ffrag;

__device__ __forceinline__ ffrag mfma16(bfrag a, bfrag b, ffrag c) {
    return __builtin_amdgcn_mfma_f32_16x16x32_bf16(a, b, c, 0, 0, 0);
}

__device__ __forceinline__ ushort f2bf(float f) {
    union { float f; unsigned u; } un;
    un.f = f;
    unsigned u = un.u;
    u += 0x7fffu + ((u >> 16) & 1u);   // RNE
    return (ushort)(u >> 16);
}

__device__ __forceinline__ uint pkbf2(float a, float b) {
    __hip_bfloat162 h = __float22bfloat162_rn(make_float2(a, b));
    union { __hip_bfloat162 h; uint u; } cv;
    cv.h = h;
    return cv.u;
}

// async global->LDS: 16B/lane; LDS dest = wave-uniform base + lane*16
__device__ __forceinline__ void gld16(const void* g, void* l) {
    __builtin_amdgcn_global_load_lds((const __attribute__((address_space(1))) void*)g,
                                     (__attribute__((address_space(3))) void*)l,
                                     16, 0, 0);
}

// ---------------- fused fp32 -> bf16 conversion ----------------
__global__ __launch_bounds__(256) void to_bf16_3(const float* __restrict__ a, ushort* __restrict__ oa, int na,
                                                 const float* __restrict__ b, ushort* __restrict__ ob, int nb,
                                                 const float* __restrict__ c, ushort* __restrict__ oc, int nc) {
    int i = (blockIdx.x * 256 + threadIdx.x) * 4;
    const float* src;
    ushort* dst;
    if (i < na)                { src = a + i;            dst = oa + i; }
    else if (i < na + nb)      { src = b + (i - na);     dst = ob + (i - na); }
    else if (i < na + nb + nc) { src = c + (i - na - nb); dst = oc + (i - na - nb); }
    else return;
    float4 v = *(const float4*)src;
    uint2 u;
    u.x = pkbf2(v.x, v.y);
    u.y = pkbf2(v.z, v.w);
    *(uint2*)dst = u;
}

// ---------------- bf16 BT-GEMM, BK=64, 512 threads, split-kb wave specialization ----------------
// Tile (MI*32) x 128. 8 waves = (kg, wm, wn): kg selects which half (kb) of the
// BK=64 tile the wave accumulates; (wm,wn) is the 2x2 spatial grid of
// (MI*16) x 64 wave-tiles. Single-buffered LDS (R7 structure — dbuf regressed
// in R8: barrier drains vmcnt regardless, and 64KB LDS cut occupancy).
// Per-wave LDS-read:MFMA ratio unchanged; waves/CU up 12 -> 16.
// End: kg=1 partial accs reduced into kg=0 via LDS (aliases staging buffer).
// Rotate swizzle: 16B chunk c of row r stored at slot (c + r) & 7.
// MODE 0: fp32 out row-major. MODE 1: qkv scatter, V transposed to [b,h,d,s].
template <int MODE, int MI>
__global__ __launch_bounds__(512, 2) void gemm_bt(const ushort* __restrict__ A,
                                                  const ushort* __restrict__ Bt,
                                                  const float* __restrict__ bias,
                                                  void* __restrict__ Cout,
                                                  int M, int N, int K) {
    __shared__ ushort smem[MI * 32 * 64 + 128 * 64];   // As | Bs; fp32 red aliases
    ushort* As = smem;
    ushort* Bs = smem + MI * 32 * 64;
    float*  red = (float*)smem;                        // 16 KB used in reduction

    const int tid  = threadIdx.x;
    const int wave = tid >> 6;
    const int lane = tid & 63;
    const int ln16 = lane & 15;
    const int quad = lane >> 4;
    const int kg = wave >> 2;          // 0/1: which kb half this wave computes
    const int w2 = wave & 3;
    const int wm = w2 >> 1, wn = w2 & 1;
    const int bm = blockIdx.x * (MI * 32);
    const int bn = blockIdx.y * 128;

    auto stage = [&](int k0) {
#pragma unroll
        for (int p = 0; p < MI / 2; ++p) {             // A: MI*256 chunks / 512 lanes
            int g0 = p * 512 + wave * 64;              // wave-uniform chunk base
            int g  = g0 + lane;
            int r  = g >> 3;
            int c  = ((g & 7) - r) & 7;                // inverse swizzle
            gld16(A + (size_t)(bm + r) * K + k0 + c * 8, (ushort*)As + g0 * 8);
        }
#pragma unroll
        for (int p = 0; p < 2; ++p) {                  // B: 1024 chunks / 512 lanes
            int g0 = p * 512 + wave * 64;
            int g  = g0 + lane;
            int r  = g >> 3;
            int c  = ((g & 7) - r) & 7;
            gld16(Bt + (size_t)(bn + r) * K + k0 + c * 8, (ushort*)Bs + g0 * 8);
        }
    };

    ffrag acc[MI][4];
#pragma unroll
    for (int mi = 0; mi < MI; ++mi)
#pragma unroll
        for (int ni = 0; ni < 4; ++ni)
            acc[mi][ni] = (ffrag){0.f, 0.f, 0.f, 0.f};

    for (int k0 = 0; k0 < K; k0 += 64) {
        stage(k0);
        __syncthreads();

        bfrag af[MI], bf[4];
#pragma unroll
        for (int mi = 0; mi < MI; ++mi) {
            int r = wm * (MI * 16) + mi * 16 + ln16;
            af[mi] = *(const bfrag*)&As[r * 64 + ((kg * 4 + quad + r) & 7) * 8];
        }
#pragma unroll
        for (int ni = 0; ni < 4; ++ni) {
            int r = wn * 64 + ni * 16 + ln16;
            bf[ni] = *(const bfrag*)&Bs[r * 64 + ((kg * 4 + quad + r) & 7) * 8];
        }
#pragma unroll
        for (int mi = 0; mi < MI; ++mi)
#pragma unroll
            for (int ni = 0; ni < 4; ++ni)
                acc[mi][ni] = mfma16(af[mi], bf[ni], acc[mi][ni]);
        __syncthreads();
    }

    // cross-kg reduction: kg=1 passes partials to kg=0 through LDS, MI phases.
    // layout: (ni*256 + w2*64 + lane) * 16B -> consecutive lanes contiguous.
#pragma unroll
    for (int mi = 0; mi < MI; ++mi) {
        if (kg == 1) {
#pragma unroll
            for (int ni = 0; ni < 4; ++ni)
                *(ffrag*)&red[(ni * 256 + w2 * 64 + lane) * 4] = acc[mi][ni];
        }
        __syncthreads();
        if (kg == 0) {
#pragma unroll
            for (int ni = 0; ni < 4; ++ni) {
                ffrag r = *(const ffrag*)&red[(ni * 256 + w2 * 64 + lane) * 4];
#pragma unroll
                for (int reg = 0; reg < 4; ++reg) acc[mi][ni][reg] += r[reg];
            }
        }
        __syncthreads();
    }

    if (kg != 0) return;

#pragma unroll
    for (int mi = 0; mi < MI; ++mi) {
#pragma unroll
        for (int ni = 0; ni < 4; ++ni) {
            int col = bn + wn * 64 + ni * 16 + ln16;
            float bc = bias[col];
            int row0 = bm + wm * (MI * 16) + mi * 16 + quad * 4;
            if (MODE == 0) {
#pragma unroll
                for (int reg = 0; reg < 4; ++reg)
                    ((float*)Cout)[(size_t)(row0 + reg) * N + col] = acc[mi][ni][reg] + bc;
            } else {
                int which = col >> 10;        // wave-uniform: 0=q 1=k 2=v
                int rem = col & 1023;
                int h = rem >> 6;
                int d = rem & 63;
                int b = row0 >> 11;
                int s0 = row0 & 2047;
                if (which == 2) {
                    // V transposed [b,h,d,s]: 4 regs = 4 consecutive s -> 8B store
                    float v0 = acc[mi][ni][0] + bc, v1 = acc[mi][ni][1] + bc;
                    float v2 = acc[mi][ni][2] + bc, v3 = acc[mi][ni][3] + bc;
                    uint2 pk;
                    pk.x = pkbf2(v0, v1);
                    pk.y = pkbf2(v2, v3);
                    size_t dst = 2ull * (BN * HN * SDIM * DDIM) +
                                 (((size_t)(b * HN + h)) * DDIM + d) * SDIM + s0;
                    *(uint2*)((ushort*)Cout + dst) = pk;
                } else {
                    float sc = (which == 0) ? 0.125f : 1.f;
#pragma unroll
                    for (int reg = 0; reg < 4; ++reg) {
                        float v = (acc[mi][ni][reg] + bc) * sc;
                        size_t dst = (size_t)which * (BN * HN * SDIM * DDIM) +
                                     (((size_t)(b * HN + h)) * SDIM + s0 + reg) * DDIM + d;
                        ((ushort*)Cout)[dst] = f2bf(v);
                    }
                }
            }
        }
    }
}

// ---------------- per-head per-tile V sums (parallel) ----------------
// grid (32, 8), 256 threads = 4 tiles x 64 d. T[bh][tile][d] = sum_{s in tile} V[d][s].
__global__ __launch_bounds__(256) void vsum_tiles(const ushort* __restrict__ Vtb,
                                                  float* __restrict__ T) {
    const int bh   = blockIdx.x;
    const int tile = blockIdx.y * 4 + (threadIdx.x >> 6);
    const int d    = threadIdx.x & 63;
    const ushort* row = Vtb + ((size_t)bh * DDIM + d) * SDIM + tile * 64;
    float s = 0.f;
#pragma unroll
    for (int j = 0; j < 64; j += 8) {
        uint4 v = *(const uint4*)(row + j);
        ushort tmp[8];
        *(uint4*)tmp = v;
#pragma unroll
        for (int e = 0; e < 8; ++e) {
            union { float f; uint u; } c;
            c.u = ((uint)tmp[e]) << 16;
            s += c.f;
        }
    }
    T[((size_t)bh * 32 + tile) * 64 + d] = s;
}

// ---------------- flash attention with near-band + closed-form far field ----------------
__global__ __launch_bounds__(512, 4) void flash_attn(const ushort* __restrict__ Qb,
                                                     const ushort* __restrict__ Kb,
                                                     const ushort* __restrict__ Vtb,
                                                     const float* __restrict__ decay_ptr,
                                                     const float* __restrict__ T,
                                                     ushort* __restrict__ Ob) {
    __shared__ ushort KVs[2][2][4096];   // [buf][K / Vt][64 rows x 8 chunks, swizzled]
    __shared__ ushort Pb[128][72];       // Q staging, then P exchange (per-wave rows)
    __shared__ float  Fv[64];            // far-field V sum per d

    const int tid  = threadIdx.x;
    const int wave = tid >> 6;
    const int lane = tid & 63;
    const int ln16 = lane & 15;
    const int quad = lane >> 4;

    const int bh = blockIdx.y;
    const int q0 = blockIdx.x * 128;
    const size_t head_off = (size_t)bh * SDIM * DDIM;
    const float absa = fabsf(decay_ptr[0]);
    const float LOG2E = 1.442695041f;
    const float M0L2 = -17.3123404f;     // -12 * log2(e)
    const float E12 = 6.144212353e-6f;   // e^-12

    // near band: tiles with a*min-dist(block q-range, tile) < 16
    int Dstar = (absa > 1e-5f) ? (int)ceilf(16.0f / absa) : (4 * SDIM);
    int lo = q0 - 63 - Dstar; if (lo < 0) lo = 0;
    int hi = q0 + 127 + Dstar; if (hi > SDIM - 1) hi = SDIM - 1;
    const int tlo = lo >> 6;
    const int thi = hi >> 6;
    const int ntiles = thi - tlo + 1;

    // far-field V sums from per-tile sums (overlapped with Q/K staging)
    if (tid < 64) {
        const float* Tp = T + (size_t)bh * 32 * 64;
        float s = 0.f;
        for (int k = 0; k < tlo; ++k)      s += Tp[k * 64 + tid];
        for (int k = thi + 1; k < 32; ++k) s += Tp[k * 64 + tid];
        Fv[tid] = s;
    }

    auto stageKV = [&](int t0, int buf) {
        int g0 = wave * 64;
        int g  = g0 + lane;
        int r  = g >> 3;
        int c  = (g - r) & 7;            // inverse swizzle
        gld16(Kb  + head_off + (size_t)(t0 + r) * DDIM + c * 8,
              (ushort*)&KVs[buf][0][0] + g0 * 8);
        gld16(Vtb + head_off + (size_t)r * SDIM + t0 + c * 8,
              (ushort*)&KVs[buf][1][0] + g0 * 8);
    };

    // stage Q (128x64) into Pb + first K/V tile into buf 0
#pragma unroll
    for (int p = 0; p < 2; ++p) {
        int idx = p * 512 + tid;
        int r = idx >> 3, c = (idx & 7) * 8;
        *(uint4*)&Pb[r][c] = *(const uint4*)(Qb + head_off + (size_t)(q0 + r) * DDIM + c);
    }
    stageKV(tlo * 64, 0);
    __syncthreads();

    bfrag aq[2];
#pragma unroll
    for (int kb = 0; kb < 2; ++kb)
        aq[kb] = *(const bfrag*)&Pb[wave * 16 + ln16][kb * 32 + quad * 8];

    bfrag ones;
#pragma unroll
    for (int i = 0; i < 8; ++i) ones[i] = (short)0x3F80;   // bf16 1.0

    float EcB[4], FcB[4], Epw[4], Fpw[4];
#pragma unroll
    for (int reg = 0; reg < 4; ++reg) {
        int cr = quad * 4 + reg;
        EcB[reg] = __expf(-absa * (float)(15 - cr));
        FcB[reg] = __expf(-absa * (float)cr);
    }
#pragma unroll
    for (int ni = 0; ni < 4; ++ni) {
        Epw[ni] = __expf(-absa * (float)(16 * (3 - ni)));
        Fpw[ni] = __expf(-absa * (float)(16 * ni));
    }
    const float Er = __expf(-absa * (float)ln16);
    const float Fr = __expf(-absa * (float)(15 - ln16));

    ffrag lacc = (ffrag){0.f, 0.f, 0.f, 0.f};
    ffrag o[4];
#pragma unroll
    for (int ni = 0; ni < 4; ++ni) o[ni] = (ffrag){0.f, 0.f, 0.f, 0.f};

    const int m = wave * 16 + ln16;

    for (int it = 0; it < ntiles; ++it) {
        const int t0 = (tlo + it) * 64;
        const int buf = it & 1;
        if (it + 1 < ntiles) stageKV(t0 + 64, buf ^ 1);   // async prefetch

        const ushort* Kt = &KVs[buf][0][0];
        const ushort* Vt = &KVs[buf][1][0];

        // S^T = K * Q^T
        ffrag sc[4];
#pragma unroll
        for (int ni = 0; ni < 4; ++ni) {
            ffrag a = (ffrag){0.f, 0.f, 0.f, 0.f};
            const int rk = ni * 16 + ln16;
#pragma unroll
            for (int kb = 0; kb < 2; ++kb) {
                bfrag kf = *(const bfrag*)&Kt[rk * 64 + ((kb * 4 + quad + rk) & 7) * 8];
                a = mfma16(kf, aq[kb], a);
            }
            sc[ni] = a;
        }

        // p = exp2(fma(s, decay*log2e, -12*log2e)); pack P to own-wave LDS rows
        const int ds = q0 + wave * 16 - t0;
        float hh = 0.f;
        if (ds >= 64)       hh = __expf(-absa * (float)(ds - 63)) * Er * LOG2E;
        else if (ds <= -16) hh = __expf(-absa * (float)(-ds - 15)) * Fr * LOG2E;

#pragma unroll
        for (int ni = 0; ni < 4; ++ni) {
            float f0, f1, f2, f3;
            if (ds >= 64) {
                float hn = hh * Epw[ni];
                f0 = hn * EcB[0]; f1 = hn * EcB[1]; f2 = hn * EcB[2]; f3 = hn * EcB[3];
            } else if (ds <= -16) {
                float hn = hh * Fpw[ni];
                f0 = hn * FcB[0]; f1 = hn * FcB[1]; f2 = hn * FcB[2]; f3 = hn * FcB[3];
            } else {
                int c0 = ni * 16 + quad * 4;
                f0 = __expf(-absa * fabsf((float)(ds + ln16 - c0)))     * LOG2E;
                f1 = __expf(-absa * fabsf((float)(ds + ln16 - c0 - 1))) * LOG2E;
                f2 = __expf(-absa * fabsf((float)(ds + ln16 - c0 - 2))) * LOG2E;
                f3 = __expf(-absa * fabsf((float)(ds + ln16 - c0 - 3))) * LOG2E;
            }
            float p0 = exp2f(fmaf(sc[ni][0], f0, M0L2));
            float p1 = exp2f(fmaf(sc[ni][1], f1, M0L2));
            float p2 = exp2f(fmaf(sc[ni][2], f2, M0L2));
            float p3 = exp2f(fmaf(sc[ni][3], f3, M0L2));
            uint2 pk;
            pk.x = pkbf2(p0, p1);
            pk.y = pkbf2(p2, p3);
            *(uint2*)&Pb[m][ni * 16 + quad * 4] = pk;   // own-wave rows: no barrier
        }

        bfrag ap[2];
#pragma unroll
        for (int kb = 0; kb < 2; ++kb)
            ap[kb] = *(const bfrag*)&Pb[m][kb * 32 + quad * 8];

#pragma unroll
        for (int kb = 0; kb < 2; ++kb)
            lacc = mfma16(ones, ap[kb], lacc);
#pragma unroll
        for (int ni = 0; ni < 4; ++ni) {
            const int rv = ni * 16 + ln16;
#pragma unroll
            for (int kb = 0; kb < 2; ++kb) {
                bfrag vf = *(const bfrag*)&Vt[rv * 64 + ((kb * 4 + quad + rv) & 7) * 8];
                o[ni] = mfma16(vf, ap[kb], o[ni]);
            }
        }
        __syncthreads();
    }

    // epilogue: add far field, normalize, store
    const float farl = E12 * (float)(SDIM - 64 * ntiles);
    const float inv = 1.f / (lacc[0] + farl);
    const int b = bh / HN, h = bh % HN;
    const int s = q0 + m;
    ushort* dst = Ob + ((size_t)(b * SDIM + s)) * EDIM + h * DDIM + quad * 4;
#pragma unroll
    for (int ni = 0; ni < 4; ++ni) {
        int d0 = ni * 16 + quad * 4;
        float v0 = (o[ni][0] + E12 * Fv[d0 + 0]) * inv;
        float v1 = (o[ni][1] + E12 * Fv[d0 + 1]) * inv;
        float v2 = (o[ni][2] + E12 * Fv[d0 + 2]) * inv;
        float v3 = (o[ni][3] + E12 * Fv[d0 + 3]) * inv;
        uint2 pk;
        pk.x = pkbf2(v0, v1);
        pk.y = pkbf2(v2, v3);
        *(uint2*)(dst + ni * 16) = pk;
    }
}

extern "C" void kernel_launch(void* const* d_in, const int* in_sizes, int n_in,
                              void* d_out, int out_size, void* d_ws, size_t ws_size,
                              hipStream_t stream) {
    const float* x      = (const float*)d_in[0];
    const float* Wqkv_w = (const float*)d_in[1];
    const float* Wqkv_b = (const float*)d_in[2];
    const float* out_w  = (const float*)d_in[3];
    const float* out_b  = (const float*)d_in[4];
    const float* dd     = (const float*)d_in[5];

    char* ws = (char*)d_ws;
    const size_t MB = 1024 * 1024;
    ushort* xb    = (ushort*)(ws + 0 * MB);    // dead after gemm<1>; T reuses it
    ushort* wqkvb = (ushort*)(ws + 8 * MB);
    ushort* owb   = (ushort*)(ws + 14 * MB);
    ushort* qkvb  = (ushort*)(ws + 16 * MB);   // q,k:[b,h,s,d] v:[b,h,d,s]
    ushort* ob    = (ushort*)(ws + 40 * MB);
    float*  Tp    = (float*)(ws + 0 * MB);     // 32*32*64*4 = 256 KB (after gemm<1>)

    const int n_x = BN * SDIM * EDIM;
    const int n_w = 3 * EDIM * EDIM;
    const int n_o = EDIM * EDIM;
    const int HSD = BN * HN * SDIM * DDIM;

    to_bf16_3<<<(n_x + n_w + n_o) / 1024, 256, 0, stream>>>(
        x, xb, n_x, Wqkv_w, wqkvb, n_w, out_w, owb, n_o);

    gemm_bt<1, 4><<<dim3(32, 24), 512, 0, stream>>>(xb, wqkvb, Wqkv_b, (void*)qkvb,
                                                    BN * SDIM, 3 * EDIM, EDIM);

    vsum_tiles<<<dim3(32, 8), 256, 0, stream>>>(qkvb + 2 * HSD, Tp);

    flash_attn<<<dim3(SDIM / 128, BN * HN), 512, 0, stream>>>(
        qkvb, qkvb + HSD, qkvb + 2 * HSD, dd, Tp, ob);

    gemm_bt<0, 2><<<dim3(64, 8), 512, 0, stream>>>(ob, owb, out_b, d_out,
                                                   BN * SDIM, EDIM, EDIM);
}

// Round 10
// 169.367 us; speedup vs baseline: 1.0220x; 1.0052x over previous
//
#include <hip/hip_runtime.h>
#include <hip/hip_bf16.h>

#define BN 2
#define SDIM 2048
#define EDIM 1024
#define HN 16
#define DDIM 64

typedef __attribute__((ext_vector_type(8))) short bfrag;
typedef __attribute__((ext_vector_type(4))) float ffrag;

__device__ __forceinline__ ffrag mfma16(bfrag a, bfrag b, ffrag c) {
    return __builtin_amdgcn_mfma_f32_16x16x32_bf16(a, b, c, 0, 0, 0);
}

__device__ __forceinline__ ushort f2bf(float f) {
    union { float f; unsigned u; } un;
    un.f = f;
    unsigned u = un.u;
    u += 0x7fffu + ((u >> 16) & 1u);   // RNE
    return (ushort)(u >> 16);
}

__device__ __forceinline__ uint pkbf2(float a, float b) {
    __hip_bfloat162 h = __float22bfloat162_rn(make_float2(a, b));
    union { __hip_bfloat162 h; uint u; } cv;
    cv.h = h;
    return cv.u;
}

// async global->LDS: 16B/lane; LDS dest = wave-uniform base + lane*16
__device__ __forceinline__ void gld16(const void* g, void* l) {
    __builtin_amdgcn_global_load_lds((const __attribute__((address_space(1))) void*)g,
                                     (__attribute__((address_space(3))) void*)l,
                                     16, 0, 0);
}

// ---------------- fused fp32 -> bf16 conversion ----------------
__global__ __launch_bounds__(256) void to_bf16_3(const float* __restrict__ a, ushort* __restrict__ oa, int na,
                                                 const float* __restrict__ b, ushort* __restrict__ ob, int nb,
                                                 const float* __restrict__ c, ushort* __restrict__ oc, int nc) {
    int i = (blockIdx.x * 256 + threadIdx.x) * 4;
    const float* src;
    ushort* dst;
    if (i < na)                { src = a + i;            dst = oa + i; }
    else if (i < na + nb)      { src = b + (i - na);     dst = ob + (i - na); }
    else if (i < na + nb + nc) { src = c + (i - na - nb); dst = oc + (i - na - nb); }
    else return;
    float4 v = *(const float4*)src;
    uint2 u;
    u.x = pkbf2(v.x, v.y);
    u.y = pkbf2(v.z, v.w);
    *(uint2*)dst = u;
}

// ---------------- bf16 BT-GEMM, BK=64, single-buffered (R6-best), small tiles ----------------
// Tile (MI*32) x 128, 256 threads = 4 waves (2x2), wave = (MI*16) x 64.
// MI=2 -> 24KB LDS -> ~6 blocks/CU co-resident: block-level overlap hides the
// per-block barrier drain (R8 dbuf and R9 split-k both failed to do this).
// Rotate swizzle: 16B chunk c of row r stored at slot (c + r) & 7.
// MODE 0: fp32 out row-major. MODE 1: qkv scatter, V transposed to [b,h,d,s].
template <int MODE, int MI>
__global__ __launch_bounds__(256) void gemm_bt(const ushort* __restrict__ A,
                                               const ushort* __restrict__ Bt,
                                               const float* __restrict__ bias,
                                               void* __restrict__ Cout,
                                               int M, int N, int K) {
    __shared__ ushort As[MI * 32 * 64];
    __shared__ ushort Bs[128 * 64];

    const int tid  = threadIdx.x;
    const int wave = tid >> 6;
    const int lane = tid & 63;
    const int ln16 = lane & 15;
    const int quad = lane >> 4;
    const int wm = wave >> 1, wn = wave & 1;
    const int bm = blockIdx.x * (MI * 32);
    const int bn = blockIdx.y * 128;

    ffrag acc[MI][4];
#pragma unroll
    for (int mi = 0; mi < MI; ++mi)
#pragma unroll
        for (int ni = 0; ni < 4; ++ni)
            acc[mi][ni] = (ffrag){0.f, 0.f, 0.f, 0.f};

    for (int k0 = 0; k0 < K; k0 += 64) {
        // A: MI*32 rows x 8 chunks = MI*256 chunks; 256 lanes -> MI rounds
#pragma unroll
        for (int p = 0; p < MI; ++p) {
            int g0 = p * 256 + wave * 64;        // wave-uniform chunk base
            int g  = g0 + lane;
            int r  = g >> 3;
            int c  = ((g & 7) - r) & 7;          // inverse swizzle
            gld16(A + (size_t)(bm + r) * K + k0 + c * 8, (ushort*)As + g0 * 8);
        }
        // B: 128 rows x 8 chunks = 1024 chunks -> 4 rounds
#pragma unroll
        for (int p = 0; p < 4; ++p) {
            int g0 = p * 256 + wave * 64;
            int g  = g0 + lane;
            int r  = g >> 3;
            int c  = ((g & 7) - r) & 7;
            gld16(Bt + (size_t)(bn + r) * K + k0 + c * 8, (ushort*)Bs + g0 * 8);
        }
        __syncthreads();

#pragma unroll
        for (int kb = 0; kb < 2; ++kb) {
            bfrag af[MI], bf[4];
#pragma unroll
            for (int mi = 0; mi < MI; ++mi) {
                int r = wm * (MI * 16) + mi * 16 + ln16;
                af[mi] = *(const bfrag*)&As[r * 64 + ((kb * 4 + quad + r) & 7) * 8];
            }
#pragma unroll
            for (int ni = 0; ni < 4; ++ni) {
                int r = wn * 64 + ni * 16 + ln16;
                bf[ni] = *(const bfrag*)&Bs[r * 64 + ((kb * 4 + quad + r) & 7) * 8];
            }
#pragma unroll
            for (int mi = 0; mi < MI; ++mi)
#pragma unroll
                for (int ni = 0; ni < 4; ++ni)
                    acc[mi][ni] = mfma16(af[mi], bf[ni], acc[mi][ni]);
        }
        __syncthreads();
    }

#pragma unroll
    for (int mi = 0; mi < MI; ++mi) {
#pragma unroll
        for (int ni = 0; ni < 4; ++ni) {
            int col = bn + wn * 64 + ni * 16 + ln16;
            float bc = bias[col];
            int row0 = bm + wm * (MI * 16) + mi * 16 + quad * 4;
            if (MODE == 0) {
#pragma unroll
                for (int reg = 0; reg < 4; ++reg)
                    ((float*)Cout)[(size_t)(row0 + reg) * N + col] = acc[mi][ni][reg] + bc;
            } else {
                int which = col >> 10;        // wave-uniform: 0=q 1=k 2=v
                int rem = col & 1023;
                int h = rem >> 6;
                int d = rem & 63;
                int b = row0 >> 11;
                int s0 = row0 & 2047;
                if (which == 2) {
                    // V transposed [b,h,d,s]: 4 regs = 4 consecutive s -> 8B store
                    float v0 = acc[mi][ni][0] + bc, v1 = acc[mi][ni][1] + bc;
                    float v2 = acc[mi][ni][2] + bc, v3 = acc[mi][ni][3] + bc;
                    uint2 pk;
                    pk.x = pkbf2(v0, v1);
                    pk.y = pkbf2(v2, v3);
                    size_t dst = 2ull * (BN * HN * SDIM * DDIM) +
                                 (((size_t)(b * HN + h)) * DDIM + d) * SDIM + s0;
                    *(uint2*)((ushort*)Cout + dst) = pk;
                } else {
                    float sc = (which == 0) ? 0.125f : 1.f;
#pragma unroll
                    for (int reg = 0; reg < 4; ++reg) {
                        float v = (acc[mi][ni][reg] + bc) * sc;
                        size_t dst = (size_t)which * (BN * HN * SDIM * DDIM) +
                                     (((size_t)(b * HN + h)) * SDIM + s0 + reg) * DDIM + d;
                        ((ushort*)Cout)[dst] = f2bf(v);
                    }
                }
            }
        }
    }
}

// ---------------- per-head per-tile V sums (parallel) ----------------
// grid (32, 8), 256 threads = 4 tiles x 64 d. T[bh][tile][d] = sum_{s in tile} V[d][s].
__global__ __launch_bounds__(256) void vsum_tiles(const ushort* __restrict__ Vtb,
                                                  float* __restrict__ T) {
    const int bh   = blockIdx.x;
    const int tile = blockIdx.y * 4 + (threadIdx.x >> 6);
    const int d    = threadIdx.x & 63;
    const ushort* row = Vtb + ((size_t)bh * DDIM + d) * SDIM + tile * 64;
    float s = 0.f;
#pragma unroll
    for (int j = 0; j < 64; j += 8) {
        uint4 v = *(const uint4*)(row + j);
        ushort tmp[8];
        *(uint4*)tmp = v;
#pragma unroll
        for (int e = 0; e < 8; ++e) {
            union { float f; uint u; } c;
            c.u = ((uint)tmp[e]) << 16;
            s += c.f;
        }
    }
    T[((size_t)bh * 32 + tile) * 64 + d] = s;
}

// ---------------- flash attention with near-band + closed-form far field ----------------
__global__ __launch_bounds__(512, 4) void flash_attn(const ushort* __restrict__ Qb,
                                                     const ushort* __restrict__ Kb,
                                                     const ushort* __restrict__ Vtb,
                                                     const float* __restrict__ decay_ptr,
                                                     const float* __restrict__ T,
                                                     ushort* __restrict__ Ob) {
    __shared__ ushort KVs[2][2][4096];   // [buf][K / Vt][64 rows x 8 chunks, swizzled]
    __shared__ ushort Pb[128][72];       // Q staging, then P exchange (per-wave rows)
    __shared__ float  Fv[64];            // far-field V sum per d

    const int tid  = threadIdx.x;
    const int wave = tid >> 6;
    const int lane = tid & 63;
    const int ln16 = lane & 15;
    const int quad = lane >> 4;

    const int bh = blockIdx.y;
    const int q0 = blockIdx.x * 128;
    const size_t head_off = (size_t)bh * SDIM * DDIM;
    const float absa = fabsf(decay_ptr[0]);
    const float LOG2E = 1.442695041f;
    const float M0L2 = -17.3123404f;     // -12 * log2(e)
    const float E12 = 6.144212353e-6f;   // e^-12

    // near band: tiles with a*min-dist(block q-range, tile) < 16
    int Dstar = (absa > 1e-5f) ? (int)ceilf(16.0f / absa) : (4 * SDIM);
    int lo = q0 - 63 - Dstar; if (lo < 0) lo = 0;
    int hi = q0 + 127 + Dstar; if (hi > SDIM - 1) hi = SDIM - 1;
    const int tlo = lo >> 6;
    const int thi = hi >> 6;
    const int ntiles = thi - tlo + 1;

    // far-field V sums from per-tile sums (overlapped with Q/K staging)
    if (tid < 64) {
        const float* Tp = T + (size_t)bh * 32 * 64;
        float s = 0.f;
        for (int k = 0; k < tlo; ++k)      s += Tp[k * 64 + tid];
        for (int k = thi + 1; k < 32; ++k) s += Tp[k * 64 + tid];
        Fv[tid] = s;
    }

    auto stageKV = [&](int t0, int buf) {
        int g0 = wave * 64;
        int g  = g0 + lane;
        int r  = g >> 3;
        int c  = (g - r) & 7;            // inverse swizzle
        gld16(Kb  + head_off + (size_t)(t0 + r) * DDIM + c * 8,
              (ushort*)&KVs[buf][0][0] + g0 * 8);
        gld16(Vtb + head_off + (size_t)r * SDIM + t0 + c * 8,
              (ushort*)&KVs[buf][1][0] + g0 * 8);
    };

    // stage Q (128x64) into Pb + first K/V tile into buf 0
#pragma unroll
    for (int p = 0; p < 2; ++p) {
        int idx = p * 512 + tid;
        int r = idx >> 3, c = (idx & 7) * 8;
        *(uint4*)&Pb[r][c] = *(const uint4*)(Qb + head_off + (size_t)(q0 + r) * DDIM + c);
    }
    stageKV(tlo * 64, 0);
    __syncthreads();

    bfrag aq[2];
#pragma unroll
    for (int kb = 0; kb < 2; ++kb)
        aq[kb] = *(const bfrag*)&Pb[wave * 16 + ln16][kb * 32 + quad * 8];

    bfrag ones;
#pragma unroll
    for (int i = 0; i < 8; ++i) ones[i] = (short)0x3F80;   // bf16 1.0

    float EcB[4], FcB[4], Epw[4], Fpw[4];
#pragma unroll
    for (int reg = 0; reg < 4; ++reg) {
        int cr = quad * 4 + reg;
        EcB[reg] = __expf(-absa * (float)(15 - cr));
        FcB[reg] = __expf(-absa * (float)cr);
    }
#pragma unroll
    for (int ni = 0; ni < 4; ++ni) {
        Epw[ni] = __expf(-absa * (float)(16 * (3 - ni)));
        Fpw[ni] = __expf(-absa * (float)(16 * ni));
    }
    const float Er = __expf(-absa * (float)ln16);
    const float Fr = __expf(-absa * (float)(15 - ln16));

    ffrag lacc = (ffrag){0.f, 0.f, 0.f, 0.f};
    ffrag o[4];
#pragma unroll
    for (int ni = 0; ni < 4; ++ni) o[ni] = (ffrag){0.f, 0.f, 0.f, 0.f};

    const int m = wave * 16 + ln16;

    for (int it = 0; it < ntiles; ++it) {
        const int t0 = (tlo + it) * 64;
        const int buf = it & 1;
        if (it + 1 < ntiles) stageKV(t0 + 64, buf ^ 1);   // async prefetch

        const ushort* Kt = &KVs[buf][0][0];
        const ushort* Vt = &KVs[buf][1][0];

        // S^T = K * Q^T
        ffrag sc[4];
#pragma unroll
        for (int ni = 0; ni < 4; ++ni) {
            ffrag a = (ffrag){0.f, 0.f, 0.f, 0.f};
            const int rk = ni * 16 + ln16;
#pragma unroll
            for (int kb = 0; kb < 2; ++kb) {
                bfrag kf = *(const bfrag*)&Kt[rk * 64 + ((kb * 4 + quad + rk) & 7) * 8];
                a = mfma16(kf, aq[kb], a);
            }
            sc[ni] = a;
        }

        // p = exp2(fma(s, decay*log2e, -12*log2e)); pack P to own-wave LDS rows
        const int ds = q0 + wave * 16 - t0;
        float hh = 0.f;
        if (ds >= 64)       hh = __expf(-absa * (float)(ds - 63)) * Er * LOG2E;
        else if (ds <= -16) hh = __expf(-absa * (float)(-ds - 15)) * Fr * LOG2E;

#pragma unroll
        for (int ni = 0; ni < 4; ++ni) {
            float f0, f1, f2, f3;
            if (ds >= 64) {
                float hn = hh * Epw[ni];
                f0 = hn * EcB[0]; f1 = hn * EcB[1]; f2 = hn * EcB[2]; f3 = hn * EcB[3];
            } else if (ds <= -16) {
                float hn = hh * Fpw[ni];
                f0 = hn * FcB[0]; f1 = hn * FcB[1]; f2 = hn * FcB[2]; f3 = hn * FcB[3];
            } else {
                int c0 = ni * 16 + quad * 4;
                f0 = __expf(-absa * fabsf((float)(ds + ln16 - c0)))     * LOG2E;
                f1 = __expf(-absa * fabsf((float)(ds + ln16 - c0 - 1))) * LOG2E;
                f2 = __expf(-absa * fabsf((float)(ds + ln16 - c0 - 2))) * LOG2E;
                f3 = __expf(-absa * fabsf((float)(ds + ln16 - c0 - 3))) * LOG2E;
            }
            float p0 = exp2f(fmaf(sc[ni][0], f0, M0L2));
            float p1 = exp2f(fmaf(sc[ni][1], f1, M0L2));
            float p2 = exp2f(fmaf(sc[ni][2], f2, M0L2));
            float p3 = exp2f(fmaf(sc[ni][3], f3, M0L2));
            uint2 pk;
            pk.x = pkbf2(p0, p1);
            pk.y = pkbf2(p2, p3);
            *(uint2*)&Pb[m][ni * 16 + quad * 4] = pk;   // own-wave rows: no barrier
        }

        bfrag ap[2];
#pragma unroll
        for (int kb = 0; kb < 2; ++kb)
            ap[kb] = *(const bfrag*)&Pb[m][kb * 32 + quad * 8];

#pragma unroll
        for (int kb = 0; kb < 2; ++kb)
            lacc = mfma16(ones, ap[kb], lacc);
#pragma unroll
        for (int ni = 0; ni < 4; ++ni) {
            const int rv = ni * 16 + ln16;
#pragma unroll
            for (int kb = 0; kb < 2; ++kb) {
                bfrag vf = *(const bfrag*)&Vt[rv * 64 + ((kb * 4 + quad + rv) & 7) * 8];
                o[ni] = mfma16(vf, ap[kb], o[ni]);
            }
        }
        __syncthreads();
    }

    // epilogue: add far field, normalize, store
    const float farl = E12 * (float)(SDIM - 64 * ntiles);
    const float inv = 1.f / (lacc[0] + farl);
    const int b = bh / HN, h = bh % HN;
    const int s = q0 + m;
    ushort* dst = Ob + ((size_t)(b * SDIM + s)) * EDIM + h * DDIM + quad * 4;
#pragma unroll
    for (int ni = 0; ni < 4; ++ni) {
        int d0 = ni * 16 + quad * 4;
        float v0 = (o[ni][0] + E12 * Fv[d0 + 0]) * inv;
        float v1 = (o[ni][1] + E12 * Fv[d0 + 1]) * inv;
        float v2 = (o[ni][2] + E12 * Fv[d0 + 2]) * inv;
        float v3 = (o[ni][3] + E12 * Fv[d0 + 3]) * inv;
        uint2 pk;
        pk.x = pkbf2(v0, v1);
        pk.y = pkbf2(v2, v3);
        *(uint2*)(dst + ni * 16) = pk;
    }
}

extern "C" void kernel_launch(void* const* d_in, const int* in_sizes, int n_in,
                              void* d_out, int out_size, void* d_ws, size_t ws_size,
                              hipStream_t stream) {
    const float* x      = (const float*)d_in[0];
    const float* Wqkv_w = (const float*)d_in[1];
    const float* Wqkv_b = (const float*)d_in[2];
    const float* out_w  = (const float*)d_in[3];
    const float* out_b  = (const float*)d_in[4];
    const float* dd     = (const float*)d_in[5];

    char* ws = (char*)d_ws;
    const size_t MB = 1024 * 1024;
    ushort* xb    = (ushort*)(ws + 0 * MB);    // dead after gemm<1>; T reuses it
    ushort* wqkvb = (ushort*)(ws + 8 * MB);
    ushort* owb   = (ushort*)(ws + 14 * MB);
    ushort* qkvb  = (ushort*)(ws + 16 * MB);   // q,k:[b,h,s,d] v:[b,h,d,s]
    ushort* ob    = (ushort*)(ws + 40 * MB);
    float*  Tp    = (float*)(ws + 0 * MB);     // 32*32*64*4 = 256 KB (after gemm<1>)

    const int n_x = BN * SDIM * EDIM;
    const int n_w = 3 * EDIM * EDIM;
    const int n_o = EDIM * EDIM;
    const int HSD = BN * HN * SDIM * DDIM;

    to_bf16_3<<<(n_x + n_w + n_o) / 1024, 256, 0, stream>>>(
        x, xb, n_x, Wqkv_w, wqkvb, n_w, out_w, owb, n_o);

    // 64x128 tiles: 1536 blocks -> ~6 blocks/CU for block-level latency overlap
    gemm_bt<1, 2><<<dim3(64, 24), 256, 0, stream>>>(xb, wqkvb, Wqkv_b, (void*)qkvb,
                                                    BN * SDIM, 3 * EDIM, EDIM);

    vsum_tiles<<<dim3(32, 8), 256, 0, stream>>>(qkvb + 2 * HSD, Tp);

    flash_attn<<<dim3(SDIM / 128, BN * HN), 512, 0, stream>>>(
        qkvb, qkvb + HSD, qkvb + 2 * HSD, dd, Tp, ob);

    gemm_bt<0, 2><<<dim3(64, 8), 256, 0, stream>>>(ob, owb, out_b, d_out,
                                                   BN * SDIM, EDIM, EDIM);
}